// Round 5
// baseline (4141.599 us; speedup 1.0000x reference)
//
#include <hip/hip_runtime.h>
#include <math.h>

// ---------------- constants ----------------
#define P1H 66
#define P1W 204
#define P1PLANE (P1H * P1W)   // 13464 floats per (b,ic) plane, zero-padded border
#define TIC 16                // ics per LDS stage in k2

// ws layout (bytes):
//   p1p   : 0           .. 110,297,088   (64*32*66*204 f32)
//   c2wT  : 110,297,088 .. 110,370,816   (32*9*64 f32, [ic][t][oc])
//   bn2sc : 110,370,816 .. 110,371,072   (64 f32)
//   bn2sh : 110,371,072 .. 110,371,328   (64 f32)
//   p2    : 112,459,776 .. 164,888,576   (64*64*32*100 f32)
//   -- after K2, p1p region is dead; f64 tail buffers reuse it --
//   hproj : 3,276,800   .. 16,384,000    (64*100*256 f64)
//   curs  : 16,384,000  .. 22,937,600    (64*50*256 f64)
//   cur1  : 22,937,600  .. 29,491,200    (64*50*256 f64)
//   cur2  : 29,491,200  .. 32,768,000    (64*50*128 f64)

// ---------------- KW: weights -> [ic][t][oc] + bn2 affine consts ------------
__global__ __launch_bounds__(256) void kw_prep(
    const float* __restrict__ c2w, const float* __restrict__ c2b,
    const float* __restrict__ g2, const float* __restrict__ b2,
    const float* __restrict__ m2, const float* __restrict__ v2,
    float* __restrict__ c2wT, float* __restrict__ bn2sc, float* __restrict__ bn2sh) {
  int blk = blockIdx.x;
  if (blk < 72) {
    int d = blk * 256 + threadIdx.x;          // dst index, 18432 total
    int ic = d / 576, rem = d - ic * 576;
    int t = rem / 64, oc = rem - t * 64;      // [ic][t][oc]
    c2wT[d] = c2w[(oc * 32 + ic) * 9 + t];
  } else if (threadIdx.x < 64) {
    int o = threadIdx.x;
    double sd = (double)g2[o] / sqrt((double)v2[o] + 1e-5);
    bn2sc[o] = (float)sd;
    bn2sh[o] = (float)(((double)c2b[o] - (double)m2[o]) * sd + (double)b2[o]);
  }
}

// ---------------- K0: zero the padded border of p1p ----------------
__global__ __launch_bounds__(256) void k0_border(float* __restrict__ p1p) {
  int plane = blockIdx.x;                       // b*32+ic, 2048 planes
  float* base = p1p + (size_t)plane * P1PLANE;
  for (int i = threadIdx.x; i < 536; i += 256) {
    int r, c;
    if (i < 204)      { r = 0;            c = i; }
    else if (i < 408) { r = 65;           c = i - 204; }
    else if (i < 472) { r = i - 408 + 1;  c = 0; }
    else              { r = i - 472 + 1;  c = 201; }
    base[r * P1W + c] = 0.f;
  }
}

// ---------------- K1: conv1(3x3,SAME) + bn1 + relu + maxpool2 ----------------
__global__ __launch_bounds__(256) void k1_conv1(
    const float* __restrict__ x,  const float* __restrict__ c1w,
    const float* __restrict__ c1b, const float* __restrict__ g1,
    const float* __restrict__ b1, const float* __restrict__ m1,
    const float* __restrict__ v1, float* __restrict__ p1p) {
  __shared__ float tile[18][67];
  __shared__ float scale[32], shift[32];
  int wx = blockIdx.x, hy = blockIdx.y, b = blockIdx.z;
  int tid = threadIdx.x;
  int gy0 = hy * 16 - 1, gx0 = wx * 64 - 1;
  const float* xb = x + (size_t)b * 128 * 400;
  for (int i = tid; i < 18 * 66; i += 256) {
    int r = i / 66, c = i - r * 66;
    int gr = gy0 + r, gc = gx0 + c;
    float v = 0.f;
    if (gr >= 0 && gr < 128 && gc >= 0 && gc < 400) v = xb[gr * 400 + gc];
    tile[r][c] = v;
  }
  if (tid < 32) {
    double s = (double)g1[tid] / sqrt((double)v1[tid] + 1e-5);
    scale[tid] = (float)s;
    shift[tid] = (float)(((double)c1b[tid] - (double)m1[tid]) * s + (double)b1[tid]);
  }
  __syncthreads();
  int tx = tid & 31, ty = tid >> 5;
  int pw = wx * 32 + tx;         // pooled col < 200
  int ph = hy * 8 + ty;          // pooled row < 64
  if (pw >= 200) return;
  float in[4][4];
#pragma unroll
  for (int r = 0; r < 4; ++r)
#pragma unroll
    for (int c = 0; c < 4; ++c) in[r][c] = tile[2 * ty + r][2 * tx + c];
  for (int ch = 0; ch < 32; ++ch) {
    float s00 = 0, s01 = 0, s10 = 0, s11 = 0;
#pragma unroll
    for (int ky = 0; ky < 3; ++ky)
#pragma unroll
      for (int kx = 0; kx < 3; ++kx) {
        float w = c1w[ch * 9 + ky * 3 + kx];   // uniform -> s_load
        s00 = fmaf(w, in[ky][kx],     s00);
        s01 = fmaf(w, in[ky][kx + 1], s01);
        s10 = fmaf(w, in[ky + 1][kx],     s10);
        s11 = fmaf(w, in[ky + 1][kx + 1], s11);
      }
    float sc = scale[ch], sh = shift[ch];
    float y00 = fmaxf(fmaf(sc, s00, sh), 0.f);
    float y01 = fmaxf(fmaf(sc, s01, sh), 0.f);
    float y10 = fmaxf(fmaf(sc, s10, sh), 0.f);
    float y11 = fmaxf(fmaf(sc, s11, sh), 0.f);
    float r = fmaxf(fmaxf(y00, y01), fmaxf(y10, y11));
    p1p[((size_t)(b * 32 + ch) * P1H + (ph + 1)) * P1W + (pw + 1)] = r;
  }
}

// ---------------- K2: conv2 v4 — lane = oc, input broadcast from LDS --------
// Block = 4 waves = 16x8 prepool tile (wave = 4 rows x 8 cols, all 64 oc).
// Input staged in LDS (TIC ics x 18x10 halo, 2 phases); lanes read the same
// LDS address -> hardware broadcast (no conflicts, DS pipe). Weights [ic][t][oc]
// -> 9 coalesced 256B loads per wave per ic into per-lane VGPRs.
__global__ __launch_bounds__(256, 6) void k2_conv2(
    const float* __restrict__ p1p, const float* __restrict__ c2wT,
    const float* __restrict__ bn2sc, const float* __restrict__ bn2sh,
    float* __restrict__ p2) {
  __shared__ float sin_[TIC][18][12];          // cols 0..9 used, 12 for alignment
  int b = blockIdx.z;
  int tile = blockIdx.x;                       // 0..99 = 4 row-tiles x 25 col-tiles
  int rt = tile / 25, ct = tile - rt * 25;
  int r0 = rt * 16, c0 = ct * 8;               // padded-coords top-left of input
  int tid = threadIdx.x;
  int wave = tid >> 6, lane = tid & 63;        // lane = oc
  int wrow = wave * 4;                         // wave's first output row in tile

  const float* pbase = p1p + (size_t)(b * 32) * P1PLANE + r0 * P1W + c0;
  float acc[4][8];
#pragma unroll
  for (int o = 0; o < 4; ++o)
#pragma unroll
    for (int j = 0; j < 8; ++j) acc[o][j] = 0.f;

  for (int phase = 0; phase < 2; ++phase) {
    int ic0 = phase * TIC;
    // ---- stage TIC ics of 18x10 halo into LDS ----
    if (phase) __syncthreads();                // protect LDS reuse
    const float* pb0 = pbase + (size_t)ic0 * P1PLANE;
    for (int e = tid; e < TIC * 180; e += 256) {
      int ic = e / 180, rem = e - ic * 180;
      int row = rem / 10, col = rem - row * 10;
      sin_[ic][row][col] = pb0[(size_t)ic * P1PLANE + row * P1W + col];
    }
    __syncthreads();
    // ---- compute from LDS ----
    for (int ic = 0; ic < TIC; ++ic) {
      float wv[9];
      const float* wp = c2wT + (size_t)(ic0 + ic) * 576 + lane;
#pragma unroll
      for (int t = 0; t < 9; ++t) wv[t] = wp[t * 64];   // coalesced 256B
#pragma unroll
      for (int l = 0; l < 6; ++l) {
        float srow[10];
#pragma unroll
        for (int c = 0; c < 10; ++c) srow[c] = sin_[ic][wrow + l][c];  // broadcast
#pragma unroll
        for (int o = 0; o < 4; ++o) {
          int ky = l - o;
          if (ky >= 0 && ky <= 2) {
#pragma unroll
            for (int xo = 0; xo < 8; ++xo) {
              acc[o][xo] = fmaf(srow[xo + 0], wv[ky * 3 + 0], acc[o][xo]);
              acc[o][xo] = fmaf(srow[xo + 1], wv[ky * 3 + 1], acc[o][xo]);
              acc[o][xo] = fmaf(srow[xo + 2], wv[ky * 3 + 2], acc[o][xo]);
            }
          }
        }
      }
    }
  }

  // ---- epilogue: bn affine + relu + 2x2 maxpool in-register, float4 stores ----
  int oc = lane;
  float sc = bn2sc[oc], sh = bn2sh[oc];
#pragma unroll
  for (int po = 0; po < 2; ++po) {
    float4 out;
    float* op = (float*)&out;
#pragma unroll
    for (int px = 0; px < 4; ++px) {
      float q00 = fmaxf(fmaf(sc, acc[2 * po][2 * px],         sh), 0.f);
      float q01 = fmaxf(fmaf(sc, acc[2 * po][2 * px + 1],     sh), 0.f);
      float q10 = fmaxf(fmaf(sc, acc[2 * po + 1][2 * px],     sh), 0.f);
      float q11 = fmaxf(fmaf(sc, acc[2 * po + 1][2 * px + 1], sh), 0.f);
      op[px] = fmaxf(fmaxf(q00, q01), fmaxf(q10, q11));
    }
    int pr = rt * 8 + wave * 2 + po;           // pooled row
    int pc = ct * 4;                           // pooled col (16B aligned)
    *(float4*)(p2 + ((size_t)(b * 64 + oc) * 32 + pr) * 100 + pc) = out;
  }
}

// ---------------- K4: freq-mean (inline) + channel_proj + LayerNorm ---------
__global__ __launch_bounds__(256) void k4_meanproj_ln(
    const float* __restrict__ p2, const float* __restrict__ pw,
    const float* __restrict__ pb, const float* __restrict__ plg,
    const float* __restrict__ plb, double* __restrict__ hproj) {
  __shared__ double hmld[64][4];
  __shared__ double sbuf[4];
  int bt0 = blockIdx.x * 4;             // 4 | 100 -> same b for all 4 rows
  int b = bt0 / 100, t0 = bt0 - b * 100;
  int tid = threadIdx.x;
  {
    int cc = tid >> 2, rr = tid & 3;
    const float* pp = p2 + (size_t)(b * 64 + cc) * 3200 + t0 + rr;
    double s = 0.0;
#pragma unroll
    for (int h = 0; h < 32; ++h) s += (double)pp[h * 100];
    hmld[cc][rr] = s * (1.0 / 32.0);
  }
  __syncthreads();
  int k = tid;
  double accv[4];
  double pbk = (double)pb[k];
#pragma unroll
  for (int r = 0; r < 4; ++r) accv[r] = pbk;
#pragma unroll 4
  for (int cc = 0; cc < 64; ++cc) {
    double w = (double)pw[cc * 256 + k];
    accv[0] = fma(hmld[cc][0], w, accv[0]);
    accv[1] = fma(hmld[cc][1], w, accv[1]);
    accv[2] = fma(hmld[cc][2], w, accv[2]);
    accv[3] = fma(hmld[cc][3], w, accv[3]);
  }
  double gk = (double)plg[k], bk = (double)plb[k];
#pragma unroll
  for (int r = 0; r < 4; ++r) {
    double v = accv[r];
#pragma unroll
    for (int off = 32; off > 0; off >>= 1) v += __shfl_down(v, off, 64);
    __syncthreads();
    if ((tid & 63) == 0) sbuf[tid >> 6] = v;
    __syncthreads();
    double mean = (sbuf[0] + sbuf[1] + sbuf[2] + sbuf[3]) * (1.0 / 256.0);
    double d = accv[r] - mean;
    double vv = d * d;
#pragma unroll
    for (int off = 32; off > 0; off >>= 1) vv += __shfl_down(vv, off, 64);
    __syncthreads();
    if ((tid & 63) == 0) sbuf[tid >> 6] = vv;
    __syncthreads();
    double var = (sbuf[0] + sbuf[1] + sbuf[2] + sbuf[3]) * (1.0 / 256.0);
    double inv = 1.0 / sqrt(var + 1e-5);
    hproj[(size_t)(bt0 + r) * 256 + k] = d * inv * gk + bk;
  }
}

// ---------------- block reduction helper (256 threads) ----------------
__device__ __forceinline__ double block_reduce_sum_256(double v, double* sbuf) {
#pragma unroll
  for (int off = 32; off > 0; off >>= 1) v += __shfl_down(v, off, 64);
  int lane = threadIdx.x & 63, wid = threadIdx.x >> 6;
  __syncthreads();
  if (lane == 0) sbuf[wid] = v;
  __syncthreads();
  return sbuf[0] + sbuf[1] + sbuf[2] + sbuf[3];
}

// ---------------- K5a: interp(x2 avg) + LayerNorm ----------------
__global__ __launch_bounds__(256) void k5a_interp_ln(
    const double* __restrict__ hproj, const float* __restrict__ ing,
    const float* __restrict__ inb, double* __restrict__ curs) {
  __shared__ double sbuf[4];
  int bs = blockIdx.x;                  // b*50 + s
  int b = bs / 50, st = bs - b * 50;
  int k = threadIdx.x;
  const double* hp = hproj + (size_t)(b * 100 + 2 * st) * 256;
  double xk = 0.5 * (hp[k] + hp[256 + k]);   // src = 2s+0.5 -> avg of pair
  double mean = block_reduce_sum_256(xk, sbuf) * (1.0 / 256.0);
  double d = xk - mean;
  double var = block_reduce_sum_256(d * d, sbuf) * (1.0 / 256.0);
  double inv = 1.0 / sqrt(var + 1e-5);
  curs[(size_t)bs * 256 + k] = d * inv * (double)ing[k] + (double)inb[k];
}

// ---------------- K5b: fc1 GEMM, 8 rows/block ----------------
__global__ __launch_bounds__(256) void k5b_fc1(
    const double* __restrict__ curs, const float* __restrict__ fc1w,
    const float* __restrict__ fc1b, double* __restrict__ cur1) {
  int row0 = blockIdx.x * 8;            // 400 blocks
  int k = threadIdx.x;
  double accv[8];
  double bk = (double)fc1b[k];
#pragma unroll
  for (int r = 0; r < 8; ++r) accv[r] = bk;
  const double* ab = curs + (size_t)row0 * 256;
#pragma unroll 4
  for (int c = 0; c < 256; ++c) {
    double w = (double)fc1w[c * 256 + k];
#pragma unroll
    for (int r = 0; r < 8; ++r)
      accv[r] = fma(ab[(size_t)r * 256 + c], w, accv[r]);   // uniform s_load
  }
#pragma unroll
  for (int r = 0; r < 8; ++r) cur1[(size_t)(row0 + r) * 256 + k] = accv[r];
}

// ---------------- K6: LIF1 scan -> spike_record ----------------
__global__ __launch_bounds__(64) void k6_lif1(
    const double* __restrict__ cur1, const float* __restrict__ beta1p,
    const float* __restrict__ thr1p, float* __restrict__ dout) {
  int b = blockIdx.x >> 2;
  int k = ((blockIdx.x & 3) << 6) + threadIdx.x;
  double beta = (double)beta1p[0];
  beta = beta < 0.0 ? 0.0 : (beta > 1.0 ? 1.0 : beta);
  double thr = (double)thr1p[0];
  double mem = 0.0;
  float* srec = dout + 128;             // spike_record after logits
  for (int t = 0; t < 50; ++t) {
    double c = cur1[(size_t)(b * 50 + t) * 256 + k];
    mem = beta * mem + c - ((mem > thr) ? thr : 0.0);   // reset uses prev mem
    srec[(size_t)(b * 50 + t) * 256 + k] = (mem > thr) ? 1.0f : 0.0f;
  }
}

// ---------------- K7: fc2 GEMM on spikes, 8 rows/block ----------------
__global__ __launch_bounds__(128) void k7_fc2(
    const float* __restrict__ dout, const float* __restrict__ fc2w,
    const float* __restrict__ fc2b, double* __restrict__ cur2) {
  int row0 = blockIdx.x * 8;            // 400 blocks
  int j = threadIdx.x;
  const float* srec = dout + 128;
  double accv[8];
  double bj = (double)fc2b[j];
#pragma unroll
  for (int r = 0; r < 8; ++r) accv[r] = bj;
#pragma unroll 4
  for (int c = 0; c < 256; ++c) {
    double w = (double)fc2w[c * 128 + j];
#pragma unroll
    for (int r = 0; r < 8; ++r)
      accv[r] = fma((double)srec[(size_t)(row0 + r) * 256 + c], w, accv[r]);  // uniform s_load
  }
#pragma unroll
  for (int r = 0; r < 8; ++r) cur2[(size_t)(row0 + r) * 128 + j] = accv[r];
}

// ---------------- K8: fused LIF2 scan + fc_out + LIF3 + logits ----------
__global__ __launch_bounds__(128) void k8_tail(
    const double* __restrict__ cur2, const float* __restrict__ fcow,
    const float* __restrict__ fcob, const float* __restrict__ beta2p,
    const float* __restrict__ thr2p, const float* __restrict__ beta3p,
    const float* __restrict__ thr3p, float* __restrict__ dout) {
  __shared__ float s2s[50][128];
  __shared__ double c3s[50][2];
  int b = blockIdx.x, j = threadIdx.x;
  double beta2 = (double)beta2p[0];
  beta2 = beta2 < 0.0 ? 0.0 : (beta2 > 1.0 ? 1.0 : beta2);
  double thr2 = (double)thr2p[0];
  double m2 = 0.0;
  for (int t = 0; t < 50; ++t) {
    double c2 = cur2[(size_t)(b * 50 + t) * 128 + j];
    m2 = beta2 * m2 + c2 - ((m2 > thr2) ? thr2 : 0.0);
    s2s[t][j] = (m2 > thr2) ? 1.0f : 0.0f;
  }
  __syncthreads();
  int t = j;
  if (t < 50) {
    double c30 = (double)fcob[0], c31 = (double)fcob[1];
#pragma unroll 4
    for (int jj = 0; jj < 128; ++jj) {
      double s = (double)s2s[t][jj];
      c30 = fma(s, (double)fcow[jj * 2 + 0], c30);
      c31 = fma(s, (double)fcow[jj * 2 + 1], c31);
    }
    c3s[t][0] = c30; c3s[t][1] = c31;
  }
  __syncthreads();
  if (j == 0) {
    double beta3 = (double)beta3p[0];
    beta3 = beta3 < 0.0 ? 0.0 : (beta3 > 1.0 ? 1.0 : beta3);
    double thr3 = (double)thr3p[0];
    double mo0 = 0.0, mo1 = 0.0, l0 = 0.0, l1 = 0.0;
    for (int tt = 0; tt < 50; ++tt) {
      mo0 = beta3 * mo0 + c3s[tt][0] - ((mo0 > thr3) ? thr3 : 0.0);
      mo1 = beta3 * mo1 + c3s[tt][1] - ((mo1 > thr3) ? thr3 : 0.0);
      l0 += mo0; l1 += mo1;
    }
    dout[b * 2 + 0] = (float)l0; dout[b * 2 + 1] = (float)l1;
  }
}

// ---------------- launch ----------------
extern "C" void kernel_launch(void* const* d_in, const int* in_sizes, int n_in,
                              void* d_out, int out_size, void* d_ws, size_t ws_size,
                              hipStream_t stream) {
  const float* x    = (const float*)d_in[0];
  const float* c1w  = (const float*)d_in[1];
  const float* c1b  = (const float*)d_in[2];
  const float* bn1g = (const float*)d_in[3];
  const float* bn1b = (const float*)d_in[4];
  const float* bn1m = (const float*)d_in[5];
  const float* bn1v = (const float*)d_in[6];
  const float* c2w  = (const float*)d_in[7];
  const float* c2b  = (const float*)d_in[8];
  const float* bn2g = (const float*)d_in[9];
  const float* bn2b = (const float*)d_in[10];
  const float* bn2m = (const float*)d_in[11];
  const float* bn2v = (const float*)d_in[12];
  const float* pw   = (const float*)d_in[13];
  const float* pb   = (const float*)d_in[14];
  const float* plg  = (const float*)d_in[15];
  const float* plb  = (const float*)d_in[16];
  const float* ing  = (const float*)d_in[17];
  const float* inb  = (const float*)d_in[18];
  const float* fc1w = (const float*)d_in[19];
  const float* fc1b = (const float*)d_in[20];
  const float* fc2w = (const float*)d_in[21];
  const float* fc2b = (const float*)d_in[22];
  const float* fcow = (const float*)d_in[23];
  const float* fcob = (const float*)d_in[24];
  const float* beta1 = (const float*)d_in[25];
  const float* thr1  = (const float*)d_in[26];
  const float* beta2 = (const float*)d_in[27];
  const float* thr2  = (const float*)d_in[28];
  const float* beta3 = (const float*)d_in[29];
  const float* thr3  = (const float*)d_in[30];

  char* ws = (char*)d_ws;
  float*  p1p   = (float*)ws;                    // 0 .. 110,297,088
  float*  c2wT  = (float*)(ws + 110297088ULL);   // strictly after p1p
  float*  bn2sc = (float*)(ws + 110370816ULL);
  float*  bn2sh = (float*)(ws + 110371072ULL);
  float*  p2    = (float*)(ws + 112459776ULL);
  double* hproj = (double*)(ws + 3276800ULL);    // tail reuses p1p (dead after k2)
  double* curs  = (double*)(ws + 16384000ULL);
  double* cur1  = (double*)(ws + 22937600ULL);
  double* cur2  = (double*)(ws + 29491200ULL);
  float* dout = (float*)d_out;

  kw_prep<<<dim3(73), 256, 0, stream>>>(c2w, c2b, bn2g, bn2b, bn2m, bn2v, c2wT, bn2sc, bn2sh);
  k0_border<<<dim3(2048), 256, 0, stream>>>(p1p);
  k1_conv1<<<dim3(7, 8, 64), 256, 0, stream>>>(x, c1w, c1b, bn1g, bn1b, bn1m, bn1v, p1p);
  k2_conv2<<<dim3(100, 1, 64), 256, 0, stream>>>(p1p, c2wT, bn2sc, bn2sh, p2);
  k4_meanproj_ln<<<dim3(1600), 256, 0, stream>>>(p2, pw, pb, plg, plb, hproj);
  k5a_interp_ln<<<dim3(3200), 256, 0, stream>>>(hproj, ing, inb, curs);
  k5b_fc1<<<dim3(400), 256, 0, stream>>>(curs, fc1w, fc1b, cur1);
  k6_lif1<<<dim3(256), 64, 0, stream>>>(cur1, beta1, thr1, dout);
  k7_fc2<<<dim3(400), 128, 0, stream>>>(dout, fc2w, fc2b, cur2);
  k8_tail<<<dim3(64), 128, 0, stream>>>(cur2, fcow, fcob, beta2, thr2, beta3, thr3, dout);
}

// Round 6
// 744.595 us; speedup vs baseline: 5.5622x; 5.5622x over previous
//
#include <hip/hip_runtime.h>
#include <math.h>

// ---------------- constants ----------------
#define P1H 66
#define P1W 204
#define P1PLANE (P1H * P1W)   // 13464 floats per (b,ic) plane, zero-padded border

// ws layout (bytes):
//   p1p   : 0           .. 110,297,088   (64*32*66*204 f32)
//   p2    : 112,459,776 .. 164,888,576   (64*64*32*100 f32)
//   -- after K2, p1p region is dead; f64 tail buffers reuse it --
//   hproj : 0           .. 13,107,200    (64*100*256 f64)
//   cur1  : 16,384,000  .. 22,937,600    (64*50*256 f64)

// ---------------- K0: zero the padded border of p1p ----------------
__global__ __launch_bounds__(256) void k0_border(float* __restrict__ p1p) {
  int plane = blockIdx.x;                       // b*32+ic, 2048 planes
  float* base = p1p + (size_t)plane * P1PLANE;
  for (int i = threadIdx.x; i < 536; i += 256) {
    int r, c;
    if (i < 204)      { r = 0;            c = i; }
    else if (i < 408) { r = 65;           c = i - 204; }
    else if (i < 472) { r = i - 408 + 1;  c = 0; }
    else              { r = i - 472 + 1;  c = 201; }
    base[r * P1W + c] = 0.f;
  }
}

// ---------------- K1: conv1(3x3,SAME) + bn1 + relu + maxpool2 ----------------
__global__ __launch_bounds__(256) void k1_conv1(
    const float* __restrict__ x,  const float* __restrict__ c1w,
    const float* __restrict__ c1b, const float* __restrict__ g1,
    const float* __restrict__ b1, const float* __restrict__ m1,
    const float* __restrict__ v1, float* __restrict__ p1p) {
  __shared__ float tile[18][67];
  __shared__ float scale[32], shift[32];
  int wx = blockIdx.x, hy = blockIdx.y, b = blockIdx.z;
  int tid = threadIdx.x;
  int gy0 = hy * 16 - 1, gx0 = wx * 64 - 1;
  const float* xb = x + (size_t)b * 128 * 400;
  for (int i = tid; i < 18 * 66; i += 256) {
    int r = i / 66, c = i - r * 66;
    int gr = gy0 + r, gc = gx0 + c;
    float v = 0.f;
    if (gr >= 0 && gr < 128 && gc >= 0 && gc < 400) v = xb[gr * 400 + gc];
    tile[r][c] = v;
  }
  if (tid < 32) {
    double s = (double)g1[tid] / sqrt((double)v1[tid] + 1e-5);
    scale[tid] = (float)s;
    shift[tid] = (float)(((double)c1b[tid] - (double)m1[tid]) * s + (double)b1[tid]);
  }
  __syncthreads();
  int tx = tid & 31, ty = tid >> 5;
  int pw = wx * 32 + tx;         // pooled col < 200
  int ph = hy * 8 + ty;          // pooled row < 64
  if (pw >= 200) return;
  float in[4][4];
#pragma unroll
  for (int r = 0; r < 4; ++r)
#pragma unroll
    for (int c = 0; c < 4; ++c) in[r][c] = tile[2 * ty + r][2 * tx + c];
  for (int ch = 0; ch < 32; ++ch) {
    float s00 = 0, s01 = 0, s10 = 0, s11 = 0;
#pragma unroll
    for (int ky = 0; ky < 3; ++ky)
#pragma unroll
      for (int kx = 0; kx < 3; ++kx) {
        float w = c1w[ch * 9 + ky * 3 + kx];   // uniform -> s_load
        s00 = fmaf(w, in[ky][kx],     s00);
        s01 = fmaf(w, in[ky][kx + 1], s01);
        s10 = fmaf(w, in[ky + 1][kx],     s10);
        s11 = fmaf(w, in[ky + 1][kx + 1], s11);
      }
    float sc = scale[ch], sh = shift[ch];
    float y00 = fmaxf(fmaf(sc, s00, sh), 0.f);
    float y01 = fmaxf(fmaf(sc, s01, sh), 0.f);
    float y10 = fmaxf(fmaf(sc, s10, sh), 0.f);
    float y11 = fmaxf(fmaf(sc, s11, sh), 0.f);
    float r = fmaxf(fmaxf(y00, y01), fmaxf(y10, y11));
    p1p[((size_t)(b * 32 + ch) * P1H + (ph + 1)) * P1W + (pw + 1)] = r;
  }
}

// ---------------- K2: conv2 (R1 structure) + XCD-aware swizzle --------------
// lane = output channel (64); wave = one 4x4-pooled (8x8 pre-pool) tile.
// Input rows are wave-uniform (scalar loads); weights per-lane, reused over
// 64 positions. Swizzle: all 50 blocks of batch b land on XCD (b&7), so the
// batch's 1.76 MB plane-set is L2-resident -> halo re-reads hit L2.
__global__ __launch_bounds__(256) void k2_conv2(
    const float* __restrict__ p1p, const float* __restrict__ c2w,
    const float* __restrict__ c2b, const float* __restrict__ g2,
    const float* __restrict__ b2, const float* __restrict__ m2,
    const float* __restrict__ v2, float* __restrict__ p2) {
  int id = blockIdx.x;                          // 0..3199
  int low3 = id & 7;
  int rest = id >> 3;                           // 0..399
  int tileq = rest % 50;
  int b = (rest / 50) * 8 + low3;               // id = ((b>>3)*50+tile)*8+(b&7)
  int wid = __builtin_amdgcn_readfirstlane((int)(threadIdx.x >> 6));
  int lane = threadIdx.x & 63;                  // = oc
  int widx = tileq * 4 + wid;                   // 0..199 tile id
  int ty = widx / 25, tx = widx - ty * 25;      // uniform
  int ph0 = ty * 4, pw0 = tx * 4;               // pooled origin
  const float* ipbase = p1p + (size_t)(b * 32) * P1PLANE + (ph0 * 2) * P1W + (pw0 * 2);
  float acc[8][8];
#pragma unroll
  for (int i = 0; i < 8; ++i)
#pragma unroll
    for (int j = 0; j < 8; ++j) acc[i][j] = 0.f;

  for (int ic = 0; ic < 32; ++ic) {
    float wv[9];
    const float* wp = c2w + ((lane * 32) + ic) * 9;
#pragma unroll
    for (int j = 0; j < 9; ++j) wv[j] = wp[j];
    const float* ip = ipbase + (size_t)ic * P1PLANE;
#pragma unroll
    for (int r = 0; r < 10; ++r) {
      float srow[10];
#pragma unroll
      for (int c = 0; c < 10; ++c) srow[c] = ip[r * P1W + c];  // uniform -> s_load
#pragma unroll
      for (int ky = 0; ky < 3; ++ky) {
        int yo = r - ky;
        if (yo >= 0 && yo <= 7) {
#pragma unroll
          for (int xo = 0; xo < 8; ++xo) {
            acc[yo][xo] = fmaf(srow[xo + 0], wv[ky * 3 + 0], acc[yo][xo]);
            acc[yo][xo] = fmaf(srow[xo + 1], wv[ky * 3 + 1], acc[yo][xo]);
            acc[yo][xo] = fmaf(srow[xo + 2], wv[ky * 3 + 2], acc[yo][xo]);
          }
        }
      }
    }
  }
  // epilogue: bn affine + relu + 2x2 maxpool, store (scattered per-lane)
  int oc = lane;
  double sd = (double)g2[oc] / sqrt((double)v2[oc] + 1e-5);
  float sc = (float)sd;
  float sh = (float)(((double)c2b[oc] - (double)m2[oc]) * sd + (double)b2[oc]);
#pragma unroll
  for (int py = 0; py < 4; ++py)
#pragma unroll
    for (int px = 0; px < 4; ++px) {
      float q00 = fmaxf(fmaf(sc, acc[2 * py][2 * px],         sh), 0.f);
      float q01 = fmaxf(fmaf(sc, acc[2 * py][2 * px + 1],     sh), 0.f);
      float q10 = fmaxf(fmaf(sc, acc[2 * py + 1][2 * px],     sh), 0.f);
      float q11 = fmaxf(fmaf(sc, acc[2 * py + 1][2 * px + 1], sh), 0.f);
      float r = fmaxf(fmaxf(q00, q01), fmaxf(q10, q11));
      p2[((size_t)(b * 64 + oc) * 32 + (ph0 + py)) * 100 + (pw0 + px)] = r;
    }
}

// ---------------- K4f: freq-mean + channel_proj + LayerNorm (proven R4/R5) --
__global__ __launch_bounds__(256) void k4_meanproj_ln(
    const float* __restrict__ p2, const float* __restrict__ pw,
    const float* __restrict__ pb, const float* __restrict__ plg,
    const float* __restrict__ plb, double* __restrict__ hproj) {
  __shared__ double hmld[64][4];
  __shared__ double sbuf[4];
  int bt0 = blockIdx.x * 4;             // 4 | 100 -> same b for all 4 rows
  int b = bt0 / 100, t0 = bt0 - b * 100;
  int tid = threadIdx.x;
  {
    int cc = tid >> 2, rr = tid & 3;
    const float* pp = p2 + (size_t)(b * 64 + cc) * 3200 + t0 + rr;
    double s = 0.0;
#pragma unroll
    for (int h = 0; h < 32; ++h) s += (double)pp[h * 100];
    hmld[cc][rr] = s * (1.0 / 32.0);
  }
  __syncthreads();
  int k = tid;
  double accv[4];
  double pbk = (double)pb[k];
#pragma unroll
  for (int r = 0; r < 4; ++r) accv[r] = pbk;
#pragma unroll 4
  for (int cc = 0; cc < 64; ++cc) {
    double w = (double)pw[cc * 256 + k];
    accv[0] = fma(hmld[cc][0], w, accv[0]);
    accv[1] = fma(hmld[cc][1], w, accv[1]);
    accv[2] = fma(hmld[cc][2], w, accv[2]);
    accv[3] = fma(hmld[cc][3], w, accv[3]);
  }
  double gk = (double)plg[k], bk = (double)plb[k];
#pragma unroll
  for (int r = 0; r < 4; ++r) {
    double v = accv[r];
#pragma unroll
    for (int off = 32; off > 0; off >>= 1) v += __shfl_down(v, off, 64);
    __syncthreads();
    if ((tid & 63) == 0) sbuf[tid >> 6] = v;
    __syncthreads();
    double mean = (sbuf[0] + sbuf[1] + sbuf[2] + sbuf[3]) * (1.0 / 256.0);
    double d = accv[r] - mean;
    double vv = d * d;
#pragma unroll
    for (int off = 32; off > 0; off >>= 1) vv += __shfl_down(vv, off, 64);
    __syncthreads();
    if ((tid & 63) == 0) sbuf[tid >> 6] = vv;
    __syncthreads();
    double var = (sbuf[0] + sbuf[1] + sbuf[2] + sbuf[3]) * (1.0 / 256.0);
    double inv = 1.0 / sqrt(var + 1e-5);
    hproj[(size_t)(bt0 + r) * 256 + k] = d * inv * gk + bk;
  }
}

// ---------------- block reduction helper (256 threads) ----------------
__device__ __forceinline__ double block_reduce_sum_256(double v, double* sbuf) {
#pragma unroll
  for (int off = 32; off > 0; off >>= 1) v += __shfl_down(v, off, 64);
  int lane = threadIdx.x & 63, wid = threadIdx.x >> 6;
  __syncthreads();
  if (lane == 0) sbuf[wid] = v;
  __syncthreads();
  return sbuf[0] + sbuf[1] + sbuf[2] + sbuf[3];
}

// ---------------- K5f: interp(x2 avg) + LayerNorm + fc1, 8 rows/block -------
// Rows are flattened (b*50+s); each row's LN is independent; normalized
// activations go to LDS (broadcast reads in the fc1 phase).
__global__ __launch_bounds__(256) void k5_fused(
    const double* __restrict__ hproj, const float* __restrict__ ing,
    const float* __restrict__ inb, const float* __restrict__ fc1w,
    const float* __restrict__ fc1b, double* __restrict__ cur1) {
  __shared__ double curs_l[8][256];
  __shared__ double sbuf[4];
  int row0 = blockIdx.x * 8;            // 400 blocks, rows 0..3199
  int k = threadIdx.x;
  double ingk = (double)ing[k], inbk = (double)inb[k];
  for (int r = 0; r < 8; ++r) {
    int bs = row0 + r;
    int b = bs / 50, st = bs - b * 50;
    const double* hp = hproj + (size_t)(b * 100 + 2 * st) * 256;
    double xk = 0.5 * (hp[k] + hp[256 + k]);   // src = 2s+0.5 -> avg of pair
    double mean = block_reduce_sum_256(xk, sbuf) * (1.0 / 256.0);
    double d = xk - mean;
    double var = block_reduce_sum_256(d * d, sbuf) * (1.0 / 256.0);
    double inv = 1.0 / sqrt(var + 1e-5);
    curs_l[r][k] = d * inv * ingk + inbk;
  }
  __syncthreads();
  double accv[8];
  double bk = (double)fc1b[k];
#pragma unroll
  for (int r = 0; r < 8; ++r) accv[r] = bk;
#pragma unroll 2
  for (int c = 0; c < 256; ++c) {
    double w = (double)fc1w[c * 256 + k];     // coalesced per-lane
#pragma unroll
    for (int r = 0; r < 8; ++r)
      accv[r] = fma(curs_l[r][c], w, accv[r]); // LDS broadcast
  }
#pragma unroll
  for (int r = 0; r < 8; ++r) cur1[(size_t)(row0 + r) * 256 + k] = accv[r];
}

// ---------------- KT: lif1 + fc2 + lif2 + fc_out + lif3 + logits, 1 blk/b ---
__global__ __launch_bounds__(256) void k_tail(
    const double* __restrict__ cur1, const float* __restrict__ fc2w,
    const float* __restrict__ fc2b, const float* __restrict__ fcow,
    const float* __restrict__ fcob, const float* __restrict__ beta1p,
    const float* __restrict__ thr1p, const float* __restrict__ beta2p,
    const float* __restrict__ thr2p, const float* __restrict__ beta3p,
    const float* __restrict__ thr3p, float* __restrict__ dout) {
  __shared__ float s1s[50][256];        // lif1 spikes (later cols 0..127 = s2)
  __shared__ double c2s[50][128];       // fc2 currents
  __shared__ double c3s[50][2];
  int b = blockIdx.x, tid = threadIdx.x;
  float* srec = dout + 128;

  // --- phase A: LIF1 scan over t, thread = channel k ---
  {
    double beta = (double)beta1p[0];
    beta = beta < 0.0 ? 0.0 : (beta > 1.0 ? 1.0 : beta);
    double thr = (double)thr1p[0];
    double mem = 0.0;
    for (int t = 0; t < 50; ++t) {
      double c = cur1[(size_t)(b * 50 + t) * 256 + tid];
      mem = beta * mem + c - ((mem > thr) ? thr : 0.0);   // reset uses prev mem
      float s = (mem > thr) ? 1.0f : 0.0f;
      srec[(size_t)(b * 50 + t) * 256 + tid] = s;
      s1s[t][tid] = s;
    }
  }
  __syncthreads();

  // --- phase B: fc2 for all (t,j); wave-uniform t, coalesced weights ---
  for (int p = 0; p < 25; ++p) {
    int tj = p * 256 + tid;
    int t = tj >> 7, j = tj & 127;
    double acc = (double)fc2b[j];
#pragma unroll 4
    for (int c = 0; c < 256; ++c)
      acc = fma((double)s1s[t][c], (double)fc2w[c * 128 + j], acc);
    c2s[t][j] = acc;
  }
  __syncthreads();

  // --- phase C: LIF2 scan, thread = channel j<128; s2 spikes -> s1s[:,0:128]
  if (tid < 128) {
    double beta = (double)beta2p[0];
    beta = beta < 0.0 ? 0.0 : (beta > 1.0 ? 1.0 : beta);
    double thr = (double)thr2p[0];
    double m2 = 0.0;
    for (int t = 0; t < 50; ++t) {
      m2 = beta * m2 + c2s[t][tid] - ((m2 > thr) ? thr : 0.0);
      s1s[t][tid] = (m2 > thr) ? 1.0f : 0.0f;
    }
  }
  __syncthreads();

  // --- phase D: fc_out per timestep, thread = t<50 ---
  if (tid < 50) {
    double c30 = (double)fcob[0], c31 = (double)fcob[1];
#pragma unroll 4
    for (int jj = 0; jj < 128; ++jj) {
      double s = (double)s1s[tid][jj];
      c30 = fma(s, (double)fcow[jj * 2 + 0], c30);
      c31 = fma(s, (double)fcow[jj * 2 + 1], c31);
    }
    c3s[tid][0] = c30; c3s[tid][1] = c31;
  }
  __syncthreads();

  // --- phase E: LIF3 scan + logits, thread 0 ---
  if (tid == 0) {
    double beta = (double)beta3p[0];
    beta = beta < 0.0 ? 0.0 : (beta > 1.0 ? 1.0 : beta);
    double thr = (double)thr3p[0];
    double mo0 = 0.0, mo1 = 0.0, l0 = 0.0, l1 = 0.0;
    for (int tt = 0; tt < 50; ++tt) {
      mo0 = beta * mo0 + c3s[tt][0] - ((mo0 > thr) ? thr : 0.0);
      mo1 = beta * mo1 + c3s[tt][1] - ((mo1 > thr) ? thr : 0.0);
      l0 += mo0; l1 += mo1;
    }
    dout[b * 2 + 0] = (float)l0; dout[b * 2 + 1] = (float)l1;
  }
}

// ---------------- launch ----------------
extern "C" void kernel_launch(void* const* d_in, const int* in_sizes, int n_in,
                              void* d_out, int out_size, void* d_ws, size_t ws_size,
                              hipStream_t stream) {
  const float* x    = (const float*)d_in[0];
  const float* c1w  = (const float*)d_in[1];
  const float* c1b  = (const float*)d_in[2];
  const float* bn1g = (const float*)d_in[3];
  const float* bn1b = (const float*)d_in[4];
  const float* bn1m = (const float*)d_in[5];
  const float* bn1v = (const float*)d_in[6];
  const float* c2w  = (const float*)d_in[7];
  const float* c2b  = (const float*)d_in[8];
  const float* bn2g = (const float*)d_in[9];
  const float* bn2b = (const float*)d_in[10];
  const float* bn2m = (const float*)d_in[11];
  const float* bn2v = (const float*)d_in[12];
  const float* pw   = (const float*)d_in[13];
  const float* pb   = (const float*)d_in[14];
  const float* plg  = (const float*)d_in[15];
  const float* plb  = (const float*)d_in[16];
  const float* ing  = (const float*)d_in[17];
  const float* inb  = (const float*)d_in[18];
  const float* fc1w = (const float*)d_in[19];
  const float* fc1b = (const float*)d_in[20];
  const float* fc2w = (const float*)d_in[21];
  const float* fc2b = (const float*)d_in[22];
  const float* fcow = (const float*)d_in[23];
  const float* fcob = (const float*)d_in[24];
  const float* beta1 = (const float*)d_in[25];
  const float* thr1  = (const float*)d_in[26];
  const float* beta2 = (const float*)d_in[27];
  const float* thr2  = (const float*)d_in[28];
  const float* beta3 = (const float*)d_in[29];
  const float* thr3  = (const float*)d_in[30];

  char* ws = (char*)d_ws;
  float*  p1p   = (float*)ws;                    // 0 .. 110,297,088
  float*  p2    = (float*)(ws + 112459776ULL);
  double* hproj = (double*)ws;                   // reuses p1p (dead after k2)
  double* cur1  = (double*)(ws + 16384000ULL);
  float* dout = (float*)d_out;

  k0_border<<<dim3(2048), 256, 0, stream>>>(p1p);
  k1_conv1<<<dim3(7, 8, 64), 256, 0, stream>>>(x, c1w, c1b, bn1g, bn1b, bn1m, bn1v, p1p);
  k2_conv2<<<dim3(3200), 256, 0, stream>>>(p1p, c2w, c2b, bn2g, bn2b, bn2m, bn2v, p2);
  k4_meanproj_ln<<<dim3(1600), 256, 0, stream>>>(p2, pw, pb, plg, plb, hproj);
  k5_fused<<<dim3(400), 256, 0, stream>>>(hproj, ing, inb, fc1w, fc1b, cur1);
  k_tail<<<dim3(64), 256, 0, stream>>>(cur1, fc2w, fc2b, fcow, fcob,
                                       beta1, thr1, beta2, thr2, beta3, thr3, dout);
}